// Round 16
// baseline (2726.683 us; speedup 1.0000x reference)
//
#include <hip/hip_runtime.h>

// 2-layer LSTM (B=256, T=512, D=64, H=256) + FC(256->4).
// 32 groups x 8 blocks; blocks 0-3: L0 quadrant q, 4-7: L1 quadrant q.
// Systolic skew: iter s computes h0(s) on L0, h1(s-1) on L1.
// Round-16: PRODUCER-CONSUMER WAVE SPECIALIZATION. 576 threads = 8 compute
// waves (r12's exact MFMA/act layout) + 1 communicator wave. The comm wave
// stages step s+1 packets (retry on embedded epoch) CONCURRENTLY with step-s
// compute, into double-buffered sB[par], publishing via LDS flags. No
// __syncthreads in the hot loop -- intra-block sync is LDS counters:
//   compute wave: spin sFlag[par]>=s -> MFMA -> spin actCnt>=8s -> part2
//     -> mfmaCnt++ -> spin mfmaCnt>=8(s+1) -> act+guard+ring store -> actCnt++
//   comm wave (t = step being staged): spin mfmaCnt>=8(t-1) [sB WAR] ->
//     load/retry packets -> write sB[t&1] -> sFlag[t&1]=t (release) -> cflag=t+1
// Cross-block protocol byte-identical to r12: u64 {epoch32|2xf16} packets,
// relaxed agent atomics, ring-4, guard tgt=s-2, memset epoch-0 = h(-1)=0.

#define TT 512
#define HH 256
#define DD 64

typedef __attribute__((ext_vector_type(2))) _Float16 h2t;
typedef __attribute__((ext_vector_type(8))) _Float16 f16x8;
typedef __attribute__((ext_vector_type(4))) float f32x4;
typedef unsigned long long u64;
typedef unsigned u32;

__device__ __forceinline__ u32 pkh(float x, float y) {
    h2t h; h.x = (_Float16)x; h.y = (_Float16)y;
    return __builtin_bit_cast(u32, h);
}
__device__ __forceinline__ float sigf(float x) { return 1.f / (1.f + __expf(-x)); }
__device__ __forceinline__ float tanhf_(float x) {
    float e = __expf(2.f * x);
    return 1.f - 2.f / (e + 1.f);   // safe at +/-inf
}
__device__ __forceinline__ f16x8 ld8(const float* p) {
    float4 u = ((const float4*)p)[0];
    float4 v = ((const float4*)p)[1];
    f16x8 r = {(_Float16)u.x, (_Float16)u.y, (_Float16)u.z, (_Float16)u.w,
               (_Float16)v.x, (_Float16)v.y, (_Float16)v.z, (_Float16)v.w};
    return r;
}
__device__ __forceinline__ u32 ld32(const u32* p) {
    return __hip_atomic_load(p, __ATOMIC_RELAXED, __HIP_MEMORY_SCOPE_AGENT);
}
__device__ __forceinline__ void st32(u32* p, u32 v) {
    __hip_atomic_store(p, v, __ATOMIC_RELAXED, __HIP_MEMORY_SCOPE_AGENT);
}
__device__ __forceinline__ u64 ld64(const u64* p) {
    return __hip_atomic_load(p, __ATOMIC_RELAXED, __HIP_MEMORY_SCOPE_AGENT);
}
__device__ __forceinline__ void st64(u64* p, u64 v) {
    __hip_atomic_store(p, v, __ATOMIC_RELAXED, __HIP_MEMORY_SCOPE_AGENT);
}
// LDS (workgroup) sync primitives
__device__ __forceinline__ int ldsLd(const int* p) {
    return __hip_atomic_load(p, __ATOMIC_ACQUIRE, __HIP_MEMORY_SCOPE_WORKGROUP);
}
__device__ __forceinline__ void ldsAdd(int* p) {
    __hip_atomic_fetch_add(p, 1, __ATOMIC_ACQ_REL, __HIP_MEMORY_SCOPE_WORKGROUP);
}
__device__ __forceinline__ void ldsStRel(int* p, int v) {
    __hip_atomic_store(p, v, __ATOMIC_RELEASE, __HIP_MEMORY_SCOPE_WORKGROUP);
}

#define R16(M) M(0) M(1) M(2) M(3) M(4) M(5) M(6) M(7) \
               M(8) M(9) M(10) M(11) M(12) M(13) M(14) M(15)

__global__ __launch_bounds__(576) void lstm_persist(
    const float* __restrict__ x,
    const float* __restrict__ Wih0, const float* __restrict__ Whh0,
    const float* __restrict__ bih0, const float* __restrict__ bhh0,
    const float* __restrict__ Wih1, const float* __restrict__ Whh1,
    const float* __restrict__ bih1, const float* __restrict__ bhh1,
    const float* __restrict__ fcW, const float* __restrict__ fcb,
    float* __restrict__ out,
    u64* h0ring, u64* h1ring, u32* cflagsA)
{
    __shared__ __align__(16) _Float16 sB[2][9216];     // dbuf: 64 ch x 144 halves
    __shared__ __align__(16) float part2[2][8][276];   // k-split partials
    __shared__ int sFlag[2];                           // step staged per parity
    __shared__ int mfmaCnt, actCnt;                    // wave completion counters

    const int tid  = threadIdx.x;
    const int g    = blockIdx.x & 31;
    const int role = blockIdx.x >> 5;
    const bool isL1 = role >= 4;
    const int q = role & 3;
    const int batch0 = g * 8;
    u64* ring0 = h0ring + (size_t)g * 4096;   // [slot4][q4][j8][hp32]
    u64* ring1 = h1ring + (size_t)g * 4096;
    u32* cflag = cflagsA + (size_t)g * 16;

    u32* const sBu = (u32*)&sB[0][0];         // 2*4608 u32 total
    for (int i = tid; i < 9216; i += 576) sBu[i] = 0;   // pads + h(-1)=0
    if (tid == 0) { sFlag[0] = -1; sFlag[1] = -1; mfmaCnt = 0; actCnt = 0; }
    __syncthreads();   // one-time init barrier

    if (tid < 512) {
        // ================= COMPUTE WAVES (r12 layout, verbatim) =============
        const int lane = tid & 63, w = tid >> 6;
        const int mw = w & 3, kh = w >> 2;
        const int bcol = lane & 15, kc = lane >> 4;

        const int R0 = mw * 256 + 64 * q + (lane & 15);
        const int R1 = R0 + 16, R2 = R0 + 32, R3 = R0 + 48;

#define DECL_TI(ti) f16x8 A##ti##_0={},A##ti##_1={},A##ti##_2={},A##ti##_3={}, \
                          A##ti##_4={},A##ti##_5={},A##ti##_6={},A##ti##_7={};
        DECL_TI(0) DECL_TI(1) DECL_TI(2) DECL_TI(3)
#undef DECL_TI
        if (isL1) {
#define LDA1(ti,j) { int k_ = (kh*8+(j))*32 + kc*8;                          \
            A##ti##_##j = ld8(k_ < 256 ? Wih1 + (size_t)R##ti*256 + k_       \
                                       : Whh1 + (size_t)R##ti*256 + (k_-256)); }
#define LDA1T(ti) LDA1(ti,0) LDA1(ti,1) LDA1(ti,2) LDA1(ti,3) \
                  LDA1(ti,4) LDA1(ti,5) LDA1(ti,6) LDA1(ti,7)
            LDA1T(0) LDA1T(1) LDA1T(2) LDA1T(3)
#undef LDA1T
#undef LDA1
        } else {
#define LDA0(ti,j) { int k_ = (kh*5+(j))*32 + kc*8;                          \
            A##ti##_##j = ld8(k_ < 64 ? Wih0 + (size_t)R##ti*64 + k_         \
                                      : Whh0 + (size_t)R##ti*256 + (k_-64)); }
#define LDA0T(ti) LDA0(ti,0) LDA0(ti,1) LDA0(ti,2) LDA0(ti,3) LDA0(ti,4)
            LDA0T(0) LDA0T(1) LDA0T(2) LDA0T(3)
#undef LDA0T
#undef LDA0
        }

        const float* bA = isL1 ? bih1 : bih0;
        const float* bB = isL1 ? bhh1 : bhh0;
        const float bz0 = bA[      64*q + lane] + bB[      64*q + lane];
        const float bz1 = bA[256 + 64*q + lane] + bB[256 + 64*q + lane];
        const float bz2 = bA[512 + 64*q + lane] + bB[512 + 64*q + lane];
        const float bz3 = bA[768 + 64*q + lane] + bB[768 + 64*q + lane];
        float cst = 0.f;

#define MST(j, ktb) { const f16x8 Bf = *(const f16x8*)(sBp + (((ktb)+(j))*4 + kc)*144 + bcol*8); \
        C0 = __builtin_amdgcn_mfma_f32_16x16x32_f16(A0_##j, Bf, C0, 0,0,0); \
        C1 = __builtin_amdgcn_mfma_f32_16x16x32_f16(A1_##j, Bf, C1, 0,0,0); \
        C2 = __builtin_amdgcn_mfma_f32_16x16x32_f16(A2_##j, Bf, C2, 0,0,0); \
        C3 = __builtin_amdgcn_mfma_f32_16x16x32_f16(A3_##j, Bf, C3, 0,0,0); }

        for (int s = 0; s <= TT; ++s) {
            const int par = s & 1;
            const bool act_ = isL1 ? (s >= 1) : (s < TT);

            if (act_) {   // wait: comm staged step s into sB[par]
                while (ldsLd(&sFlag[par]) < s) __builtin_amdgcn_s_sleep(1);
            }
            f32x4 C0 = {0,0,0,0}, C1 = {0,0,0,0}, C2 = {0,0,0,0}, C3 = {0,0,0,0};
            if (act_) {
                const _Float16* sBp = &sB[par][0];
                if (isL1) {
                    const int ktb = kh * 8;
                    MST(0,ktb) MST(1,ktb) MST(2,ktb) MST(3,ktb)
                    MST(4,ktb) MST(5,ktb) MST(6,ktb) MST(7,ktb)
                } else {
                    const int ktb = kh * 5;
                    MST(0,ktb) MST(1,ktb) MST(2,ktb) MST(3,ktb) MST(4,ktb)
                }
            }
            u32 cpre = 0u;
            if (act_ && lane < 8) cpre = ld32(&cflag[lane]);

            // part2 WAR: all acts of step s-1 done
            while (ldsLd(&actCnt) < 8 * s) __builtin_amdgcn_s_sleep(1);
            if (act_ && bcol < 8) {
                *(f32x4*)&part2[kh][bcol][mw*64 +  0 + kc*4] = C0;
                *(f32x4*)&part2[kh][bcol][mw*64 + 16 + kc*4] = C1;
                *(f32x4*)&part2[kh][bcol][mw*64 + 32 + kc*4] = C2;
                *(f32x4*)&part2[kh][bcol][mw*64 + 48 + kc*4] = C3;
            }
            if (lane == 0) ldsAdd(&mfmaCnt);
            // act gate: all waves' part2(s) written
            while (ldsLd(&mfmaCnt) < 8 * (s + 1)) __builtin_amdgcn_s_sleep(1);

            if (act_) {
                float s0 = part2[0][w][      lane] + part2[1][w][      lane] + bz0;
                float s1 = part2[0][w][ 64 + lane] + part2[1][w][ 64 + lane] + bz1;
                float s2 = part2[0][w][128 + lane] + part2[1][w][128 + lane] + bz2;
                float s3 = part2[0][w][192 + lane] + part2[1][w][192 + lane] + bz3;
                float fi = sigf(s0), ff = sigf(s1), fg = tanhf_(s2), fo = sigf(s3);
                cst = ff * cst + fi * fg;
                float h = fo * tanhf_(cst);
                float hn = __shfl_down(h, 1);
                u32 hw = pkh(h, hn);

                const int tgt = s - 2;   // ring-overwrite guard (r12 tgt)
                while (!__all(lane >= 8 || (int)cpre >= tgt)) {
                    __builtin_amdgcn_s_sleep(1);
                    if (lane < 8) cpre = ld32(&cflag[lane]);
                }
                if (!(lane & 1)) {   // packet: {epoch s+1 | 2 x f16}
                    u64 v = ((u64)(u32)(s + 1) << 32) | (u64)hw;
                    u64* dst = (isL1 ? ring1 + (size_t)((s - 1) & 3) * 1024
                                     : ring0 + (size_t)(s & 3) * 1024)
                               + q * 256 + w * 32 + (lane >> 1);
                    st64(dst, v);
                }
            }
            if (lane == 0) ldsAdd(&actCnt);
        }
#undef MST
    } else {
        // ===================== COMMUNICATOR WAVE ============================
        const int l = tid - 512;                 // 0..63
        const int tmin = isL1 ? 1 : 0;
        const int tmax = isL1 ? TT : TT - 1;
        for (int t = tmin; t <= tmax; ++t) {
            // WAR: sB[t&1] last read at step t-2 by all 8 compute waves
            if (t >= 2) {
                while (ldsLd(&mfmaCnt) < 8 * (t - 1)) __builtin_amdgcn_s_sleep(1);
            }
            u32* dst = sBu + (t & 1) * 4608;
            const u64* b0 = ring0 + (size_t)((t - 1) & 3) * 1024;
            const u32 e0 = (u32)t;
            // h0(t-1): 1024 u64 over 64 lanes = 16 per lane, coalesced per r
#define LD0(r) u64 va##r = ld64(b0 + (r) * 64 + l);
            R16(LD0)
#undef LD0
            if (isL1) {
                const u64* b1 = ring1 + (size_t)((t - 2) & 3) * 1024;
                const u32 e1 = (t >= 2) ? (u32)t : 0u;
#define LD1(r) u64 vb##r = ld64(b1 + (r) * 64 + l);
                R16(LD1)
#undef LD1
                u32 remA = 0xFFFFu, remB = 0xFFFFu;
                for (;;) {
#define TRYA(r) if ((remA >> (r)) & 1) { if ((u32)(va##r >> 32) == e0) {            \
                    int idx = (r) * 64 + l;                                          \
                    int q_ = idx >> 8, j_ = (idx >> 5) & 7;                          \
                    int n_ = 32 * q_ + (idx & 31);                                   \
                    dst[(0 + (n_ >> 2)) * 72 + j_ * 4 + (n_ & 3)] = (u32)va##r;      \
                    remA &= ~(1u << (r)); } }
                    R16(TRYA)
#undef TRYA
#define TRYB(r) if ((remB >> (r)) & 1) { if ((u32)(vb##r >> 32) == e1) {            \
                    int idx = (r) * 64 + l;                                          \
                    int q_ = idx >> 8, j_ = (idx >> 5) & 7;                          \
                    int n_ = 32 * q_ + (idx & 31);                                   \
                    dst[(32 + (n_ >> 2)) * 72 + j_ * 4 + (n_ & 3)] = (u32)vb##r;     \
                    remB &= ~(1u << (r)); } }
                    R16(TRYB)
#undef TRYB
                    if (!(remA | remB)) break;
#define RLA(r) if ((remA >> (r)) & 1) va##r = ld64(b0 + (r) * 64 + l);
                    R16(RLA)
#undef RLA
#define RLB(r) if ((remB >> (r)) & 1) vb##r = ld64(ring1 + (size_t)((t-2)&3)*1024 + (r)*64 + l);
                    R16(RLB)
#undef RLB
                }
            } else {
                // x(t) -> chunks 0..7 (no peer dependency)
                const int j = l >> 3, c8 = l & 7;
                const float4* xrow = (const float4*)(
                    x + ((size_t)(batch0 + j) * TT + t) * DD);
                float4 xa = xrow[2 * c8], xb = xrow[2 * c8 + 1];
                u32 remA = 0xFFFFu;
                for (;;) {
#define TRYA(r) if ((remA >> (r)) & 1) { if ((u32)(va##r >> 32) == e0) {            \
                    int idx = (r) * 64 + l;                                          \
                    int q_ = idx >> 8, j_ = (idx >> 5) & 7;                          \
                    int n_ = 32 * q_ + (idx & 31);                                   \
                    dst[(8 + (n_ >> 2)) * 72 + j_ * 4 + (n_ & 3)] = (u32)va##r;      \
                    remA &= ~(1u << (r)); } }
                    R16(TRYA)
#undef TRYA
                    if (!remA) break;
#define RLA(r) if ((remA >> (r)) & 1) va##r = ld64(b0 + (r) * 64 + l);
                    R16(RLA)
#undef RLA
                }
                const int xb0 = c8 * 72 + j * 4;
                dst[xb0]     = pkh(xa.x, xa.y);
                dst[xb0 + 1] = pkh(xa.z, xa.w);
                dst[xb0 + 2] = pkh(xb.x, xb.y);
                dst[xb0 + 3] = pkh(xb.z, xb.w);
            }
            ldsStRel(&sFlag[t & 1], t);          // publish: step t staged
            st32(&cflag[role], (u32)(t + 1));    // cross-block: staged step t
        }
    }
    __syncthreads();   // one-time: everyone done before FC reuses sB

    // ---- final FC on h1(TT-1): ring1 slot 3, epoch TT+1 (role==4 block) ----
    if (isL1 && q == 0) {
        if (tid < 512) {
            const u32 ef = (u32)(TT + 1);
            const int n0  = tid & 127;
            const int jj0 = tid >> 7, jj1 = 4 + jj0;
            const u64* b = ring1 + 3 * 1024 + ((size_t)(n0 >> 5) << 8) + (n0 & 31);
            const u64* a0 = b + jj0 * 32;
            const u64* a1 = b + jj1 * 32;
            u64 v0 = ld64(a0), v1 = ld64(a1);
            for (;;) {
                bool k0 = ((u32)(v0 >> 32) == ef), k1 = ((u32)(v1 >> 32) == ef);
                if (k0 & k1) break;
                if (!k0) v0 = ld64(a0);
                if (!k1) v1 = ld64(a1);
            }
            sBu[jj0 * 128 + n0] = (u32)v0;   // flat [batch][128 u32]
            sBu[jj1 * 128 + n0] = (u32)v1;
        }
        __syncthreads();
        if (tid < 512) {
            const int j = tid >> 6, l2 = tid & 63;
            const int o = l2 >> 4, kk = l2 & 15;
            const _Float16* hs = &sB[0][0];
            float ssum = 0.f;
#pragma unroll
            for (int m = 0; m < 16; ++m) {
                int k = kk * 16 + m;
                ssum += (float)hs[j * 256 + k] * fcW[o * HH + k];
            }
#pragma unroll
            for (int off = 8; off; off >>= 1) ssum += __shfl_down(ssum, off);
            if (kk == 0) out[(batch0 + j) * 4 + o] = ssum + fcb[o];
        }
    }
}

extern "C" void kernel_launch(void* const* d_in, const int* in_sizes, int n_in,
                              void* d_out, int out_size, void* d_ws, size_t ws_size,
                              hipStream_t stream)
{
    (void)in_sizes; (void)n_in; (void)out_size; (void)ws_size;
    const float* x    = (const float*)d_in[0];
    const float* Wih0 = (const float*)d_in[1];
    const float* Whh0 = (const float*)d_in[2];
    const float* bih0 = (const float*)d_in[3];
    const float* bhh0 = (const float*)d_in[4];
    const float* Wih1 = (const float*)d_in[5];
    const float* Whh1 = (const float*)d_in[6];
    const float* bih1 = (const float*)d_in[7];
    const float* bhh1 = (const float*)d_in[8];
    const float* fcW  = (const float*)d_in[9];
    const float* fcb  = (const float*)d_in[10];
    float* out = (float*)d_out;

    // ws: h0ring 1MB (32 grp x 4 slot x 1024 u64) | h1ring 1MB | cflags 2KB
    u64* h0ring = (u64*)d_ws;
    u64* h1ring = (u64*)((char*)d_ws + 1048576);
    u32* cflags = (u32*)((char*)d_ws + 2097152);

    hipMemsetAsync(d_ws, 0, 2097152 + 2048, stream);   // epoch 0 == h(-1)=0

    lstm_persist<<<dim3(256), dim3(576), 0, stream>>>(
        x, Wih0, Whh0, bih0, bhh0, Wih1, Whh1, bih1, bhh1, fcW, fcb, out,
        h0ring, h1ring, cflags);
}

// Round 17
// 1245.898 us; speedup vs baseline: 2.1885x; 2.1885x over previous
//
#include <hip/hip_runtime.h>

// 2-layer LSTM (B=256, T=512, D=64, H=256) + FC(256->4).
// FINAL (restoration of round-8 best: 1278us). 32 groups x 8 blocks; blocks
// 0-3: layer 0 quadrant q, 4-7: layer 1 quadrant q. Systolic skew: iter s
// computes h0(s) on L0 and h1(s-1) on L1.
// Exchange: u64 packets {epoch32|2xf16} via relaxed agent-scope atomics
// (the only verified-correct cross-block path; per-XCD L2s non-coherent),
// ring-4 slots, slack-2 cflag guard, 2 barriers/step. MFMA 16x16x32 f16 with
// weights register-resident as named A-fragment SSA values (4Mx2K waves,
// 100 VGPR). Own-quadrant h written straight into own sB (no ring RTT).
//
// Plateau evidence (9 structural variants, all regressed or null):
//   decoupled flags / parallel staging issue / sc0-L2 fast path (hang) /
//   early pre-issue / two-stream x2 / skew-2 fresh-last / comm-wave
//   specialization. Period = compute (~0.85us) + L3 visibility (~1.6us);
//   the latter is structural: serial recurrence, state split across 8 CUs
//   (register capacity forces the split), no independent work to hide it.

#define TT 512
#define HH 256
#define DD 64

typedef __attribute__((ext_vector_type(2))) _Float16 h2t;
typedef __attribute__((ext_vector_type(8))) _Float16 f16x8;
typedef __attribute__((ext_vector_type(4))) float f32x4;
typedef unsigned long long u64;
typedef unsigned u32;

__device__ __forceinline__ u32 pkh(float x, float y) {
    h2t h; h.x = (_Float16)x; h.y = (_Float16)y;
    return __builtin_bit_cast(u32, h);
}
__device__ __forceinline__ float sigf(float x) { return 1.f / (1.f + __expf(-x)); }
__device__ __forceinline__ float tanhf_(float x) {
    float e = __expf(2.f * x);
    return 1.f - 2.f / (e + 1.f);   // safe at +/-inf
}
__device__ __forceinline__ f16x8 ld8(const float* p) {
    float4 u = ((const float4*)p)[0];
    float4 v = ((const float4*)p)[1];
    f16x8 r = {(_Float16)u.x, (_Float16)u.y, (_Float16)u.z, (_Float16)u.w,
               (_Float16)v.x, (_Float16)v.y, (_Float16)v.z, (_Float16)v.w};
    return r;
}
__device__ __forceinline__ u32 ld32(const u32* p) {
    return __hip_atomic_load(p, __ATOMIC_RELAXED, __HIP_MEMORY_SCOPE_AGENT);
}
__device__ __forceinline__ void st32(u32* p, u32 v) {
    __hip_atomic_store(p, v, __ATOMIC_RELAXED, __HIP_MEMORY_SCOPE_AGENT);
}
__device__ __forceinline__ u64 ld64(const u64* p) {
    return __hip_atomic_load(p, __ATOMIC_RELAXED, __HIP_MEMORY_SCOPE_AGENT);
}
__device__ __forceinline__ void st64(u64* p, u64 v) {
    __hip_atomic_store(p, v, __ATOMIC_RELAXED, __HIP_MEMORY_SCOPE_AGENT);
}

__global__ __launch_bounds__(512, 2) void lstm_persist(
    const float* __restrict__ x,
    const float* __restrict__ Wih0, const float* __restrict__ Whh0,
    const float* __restrict__ bih0, const float* __restrict__ bhh0,
    const float* __restrict__ Wih1, const float* __restrict__ Whh1,
    const float* __restrict__ bih1, const float* __restrict__ bhh1,
    const float* __restrict__ fcW, const float* __restrict__ fcb,
    float* __restrict__ out,
    u64* h0ring, u64* h1ring, u32* cflagsA)
{
    __shared__ __align__(16) _Float16 sB[9216];        // 64 chunks x 144 halves
    __shared__ __align__(16) float part2[2][8][276];   // k-split partials

    const int tid  = threadIdx.x;
    const int g    = blockIdx.x & 31;
    const int role = blockIdx.x >> 5;
    const bool isL1 = role >= 4;
    const int q = role & 3;
    const int batch0 = g * 8;
    u64* ring0 = h0ring + (size_t)g * 4096;   // [slot4][q4][j8][hp32]
    u64* ring1 = h1ring + (size_t)g * 4096;
    u32* cflag = cflagsA + (size_t)g * 16;

    const int lane = tid & 63, w = tid >> 6;
    const int mw = w & 3, kh = w >> 2;
    const int bcol = lane & 15, kc = lane >> 4;

    // packet geometry (fixed per thread): p = tid + pp*512; n = p&127 same both
    const int n_ = tid & 127;
    const int jA = tid >> 7;          // batch for pp=0
    const int jB = 4 + (tid >> 7);    // batch for pp=1
    const int nq = n_ >> 5;           // quadrant of my packets

    // ---- A-fragment rows: wave mw owns gate mw; tiles ti=0..3 ----
    const int R0 = mw * 256 + 64 * q + (lane & 15);
    const int R1 = R0 + 16, R2 = R0 + 32, R3 = R0 + 48;

#define DECL_TI(ti) f16x8 A##ti##_0={},A##ti##_1={},A##ti##_2={},A##ti##_3={}, \
                          A##ti##_4={},A##ti##_5={},A##ti##_6={},A##ti##_7={};
    DECL_TI(0) DECL_TI(1) DECL_TI(2) DECL_TI(3)
#undef DECL_TI

    if (isL1) {
#define LDA1(ti,j) { int k_ = (kh*8+(j))*32 + kc*8;                          \
        A##ti##_##j = ld8(k_ < 256 ? Wih1 + (size_t)R##ti*256 + k_           \
                                   : Whh1 + (size_t)R##ti*256 + (k_-256)); }
#define LDA1T(ti) LDA1(ti,0) LDA1(ti,1) LDA1(ti,2) LDA1(ti,3) \
                  LDA1(ti,4) LDA1(ti,5) LDA1(ti,6) LDA1(ti,7)
        LDA1T(0) LDA1T(1) LDA1T(2) LDA1T(3)
#undef LDA1T
#undef LDA1
    } else if (kh == 0) {
#define LDA0(ti,j) { int k_ = (0*5+(j))*32 + kc*8;                           \
        A##ti##_##j = ld8(k_ < 64 ? Wih0 + (size_t)R##ti*64 + k_             \
                                  : Whh0 + (size_t)R##ti*256 + (k_-64)); }
#define LDA0T(ti) LDA0(ti,0) LDA0(ti,1) LDA0(ti,2) LDA0(ti,3) LDA0(ti,4)
        LDA0T(0) LDA0T(1) LDA0T(2) LDA0T(3)
#undef LDA0T
#undef LDA0
    } else {
#define LDA0(ti,j) { int k_ = (1*5+(j))*32 + kc*8;                           \
        A##ti##_##j = ld8(k_ < 64 ? Wih0 + (size_t)R##ti*64 + k_             \
                                  : Whh0 + (size_t)R##ti*256 + (k_-64)); }
#define LDA0T(ti) LDA0(ti,0) LDA0(ti,1) LDA0(ti,2) LDA0(ti,3) LDA0(ti,4)
        LDA0T(0) LDA0T(1) LDA0T(2) LDA0T(3)
#undef LDA0T
#undef LDA0
    }

    // ---- activation duty: thread (lane = h-idx in quadrant, w = batch) ----
    const float* bA = isL1 ? bih1 : bih0;
    const float* bB = isL1 ? bhh1 : bhh0;
    const float bz0 = bA[      64*q + lane] + bB[      64*q + lane];
    const float bz1 = bA[256 + 64*q + lane] + bB[256 + 64*q + lane];
    const float bz2 = bA[512 + 64*q + lane] + bB[512 + 64*q + lane];
    const float bz3 = bA[768 + 64*q + lane] + bB[768 + 64*q + lane];
    float cst = 0.f;

    u32* const sBu = (u32*)sB;
    for (int i = tid; i < 4608; i += 512) sBu[i] = 0;   // incl. pad rows 8-15
    __syncthreads();   // zero-fill complete before x(0) staging

    // prologue: h(-1)=0 already in zeroed sB; stage only x(0)
    if (!isL1 && tid >= 256 && tid < 384) {
        int t2 = tid - 256, j = t2 >> 4, c = t2 & 15;
        float4 v = ((const float4*)(x + ((size_t)(batch0 + j) * TT) * DD))[c];
        int bidx = (c >> 1) * 72 + j * 4 + (c & 1) * 2;
        sBu[bidx]     = pkh(v.x, v.y);
        sBu[bidx + 1] = pkh(v.z, v.w);
    }

    for (int s = 0; s <= TT; ++s) {
        __syncthreads();   // staging for step s complete block-wide
        if (tid == 0) st32(&cflag[role], (u32)(s + 1));   // CF: staged step s

        const bool act_ = isL1 ? (s >= 1) : (s < TT);
        const int  snx  = s + 1;
        const bool stg0 = (!isL1) && (snx < TT);
        const bool stg1 = isL1 && (snx <= TT);

        // pre-issue ring-guard loads (checked after act; RTT hidden under MFMA)
        u32 cpre = 0xFFFFFFFFu;
        if (act_ && lane < 8) cpre = ld32(&cflag[lane]);

        if (act_) {
            f32x4 C0 = {0,0,0,0}, C1 = {0,0,0,0}, C2 = {0,0,0,0}, C3 = {0,0,0,0};
#define MST(j, ktb) { const f16x8 Bf = *(const f16x8*)(sB + (((ktb)+(j))*4 + kc)*144 + bcol*8); \
            C0 = __builtin_amdgcn_mfma_f32_16x16x32_f16(A0_##j, Bf, C0, 0,0,0); \
            C1 = __builtin_amdgcn_mfma_f32_16x16x32_f16(A1_##j, Bf, C1, 0,0,0); \
            C2 = __builtin_amdgcn_mfma_f32_16x16x32_f16(A2_##j, Bf, C2, 0,0,0); \
            C3 = __builtin_amdgcn_mfma_f32_16x16x32_f16(A3_##j, Bf, C3, 0,0,0); }
            if (isL1) {
                const int ktb = kh * 8;
                MST(0,ktb) MST(1,ktb) MST(2,ktb) MST(3,ktb)
                MST(4,ktb) MST(5,ktb) MST(6,ktb) MST(7,ktb)
            } else {
                const int ktb = kh * 5;
                MST(0,ktb) MST(1,ktb) MST(2,ktb) MST(3,ktb) MST(4,ktb)
            }
#undef MST
            if (bcol < 8) {   // C: col=batch(bcol), row=(kc)*4+reg within tile
                *(f32x4*)&part2[kh][bcol][mw*64 +  0 + kc*4] = C0;
                *(f32x4*)&part2[kh][bcol][mw*64 + 16 + kc*4] = C1;
                *(f32x4*)&part2[kh][bcol][mw*64 + 32 + kc*4] = C2;
                *(f32x4*)&part2[kh][bcol][mw*64 + 48 + kc*4] = C3;
            }
        }
        __syncthreads();   // part2 ready; all sB reads of step s done

        // ---- activation; own-direct LDS write + ring store ----
        if (act_) {
            float s0 = part2[0][w][      lane] + part2[1][w][      lane] + bz0;
            float s1 = part2[0][w][ 64 + lane] + part2[1][w][ 64 + lane] + bz1;
            float s2 = part2[0][w][128 + lane] + part2[1][w][128 + lane] + bz2;
            float s3 = part2[0][w][192 + lane] + part2[1][w][192 + lane] + bz3;
            float fi = sigf(s0), ff = sigf(s1), fg = tanhf_(s2), fo = sigf(s3);
            cst = ff * cst + fi * fg;
            float h = fo * tanhf_(cst);
            float hn = __shfl_down(h, 1);
            u32 hw = pkh(h, hn);

            if (!(lane & 1)) {   // own quadrant straight into own sB (step s+1)
                int nn = (64 * q + lane) >> 1;          // 32q + lane/2
                int base = isL1 ? 32 : 8;
                sBu[(base + (nn >> 2)) * 72 + w * 4 + (nn & 3)] = hw;
            }

            // ring-overwrite guard: all 8 blocks staged step s-2 (slack 2)
            const int tgt = s - 2;
            while (!__all(lane >= 8 || (int)cpre >= tgt)) {
                __builtin_amdgcn_s_sleep(1);
                if (lane < 8) cpre = ld32(&cflag[lane]);
            }
            if (!(lane & 1)) {   // packet: {epoch s+1 | 2 x f16}
                u64 v = ((u64)(u32)(s + 1) << 32) | (u64)hw;
                u64* dst = (isL1 ? ring1 + (size_t)((s - 1) & 3) * 1024
                                 : ring0 + (size_t)(s & 3) * 1024)
                           + q * 256 + w * 32 + (lane >> 1);
                st64(dst, v);
            }
        }

        // ---- finish staging for s+1: issue loads, retry until epochs match ----
        if (stg0 || stg1) {
            u64 v0A = 0, v0B = 0, v1A = 0, v1B = 0;
            bool k0A = true, k0B = true, k1A = true, k1B = true;
            const u64 *p0A = nullptr, *p0B = nullptr, *p1A = nullptr, *p1B = nullptr;
            if (!(!isL1 && nq == q)) {   // L0 skips own h0 quadrant (own-direct)
                const u64* b0 = ring0 + (size_t)((snx - 1) & 3) * 1024
                                + (nq << 8) + (n_ & 31);
                p0A = b0 + jA * 32; p0B = b0 + jB * 32;
                v0A = ld64(p0A); v0B = ld64(p0B);
                k0A = false; k0B = false;
            }
            if (stg1 && !(nq == q && snx >= 2)) {   // L1 skips own h1 (snx>=2)
                const u64* b1 = ring1 + (size_t)((snx + 2) & 3) * 1024
                                + (nq << 8) + (n_ & 31);
                p1A = b1 + jA * 32; p1B = b1 + jB * 32;
                v1A = ld64(p1A); v1B = ld64(p1B);
                k1A = false; k1B = false;
            }
            float4 xreg;
            const bool doX = stg0 && (tid >= 256) && (tid < 384);
            if (doX) {
                int t2 = tid - 256, j = t2 >> 4, c = t2 & 15;
                xreg = ((const float4*)(x + ((size_t)(batch0 + j) * TT + snx) * DD))[c];
            }
            const u32 e0 = (u32)snx;
            const u32 e1 = (snx >= 2) ? (u32)snx : 0u;
            for (;;) {
                if (!k0A && (u32)(v0A >> 32) == e0) k0A = true;
                if (!k0B && (u32)(v0B >> 32) == e0) k0B = true;
                if (!k1A && (u32)(v1A >> 32) == e1) k1A = true;
                if (!k1B && (u32)(v1B >> 32) == e1) k1B = true;
                if (k0A & k0B & k1A & k1B) break;
                if (!k0A) v0A = ld64(p0A);
                if (!k0B) v0B = ld64(p0B);
                if (!k1A) v1A = ld64(p1A);
                if (!k1B) v1B = ld64(p1B);
            }
            if (p0A) {
                const int base = isL1 ? 0 : 8;
                sBu[(base + (n_ >> 2)) * 72 + jA * 4 + (n_ & 3)] = (u32)v0A;
                sBu[(base + (n_ >> 2)) * 72 + jB * 4 + (n_ & 3)] = (u32)v0B;
            }
            if (p1A) {
                sBu[(32 + (n_ >> 2)) * 72 + jA * 4 + (n_ & 3)] = (u32)v1A;
                sBu[(32 + (n_ >> 2)) * 72 + jB * 4 + (n_ & 3)] = (u32)v1B;
            }
            if (doX) {
                int t2 = tid - 256, j = t2 >> 4, c = t2 & 15;
                int bidx = (c >> 1) * 72 + j * 4 + (c & 1) * 2;
                sBu[bidx]     = pkh(xreg.x, xreg.y);
                sBu[bidx + 1] = pkh(xreg.z, xreg.w);
            }
        }
    }

    // ---- final FC on h1(TT-1): slot 3, epoch TT+1; role-4 block per group ----
    if (isL1 && q == 0) {
        const u32 ef = (u32)(TT + 1);
#pragma unroll
        for (int pp = 0; pp < 2; ++pp) {
            int p = tid + pp * 512;
            int j = p >> 7, n = p & 127;
            const u64* a = ring1 + 3 * 1024 + (n >> 5) * 256 + j * 32 + (n & 31);
            u64 v;
            do { v = ld64(a); } while ((u32)(v >> 32) != ef);
            sBu[j * 128 + n] = (u32)v;   // flat [batch][128 u32]
        }
        __syncthreads();
        const int j = tid >> 6, l2 = tid & 63;
        const int o = l2 >> 4, kk = l2 & 15;
        float ssum = 0.f;
#pragma unroll
        for (int m = 0; m < 16; ++m) {
            int k = kk * 16 + m;
            ssum += (float)sB[j * 256 + k] * fcW[o * HH + k];
        }
#pragma unroll
        for (int off = 8; off; off >>= 1) ssum += __shfl_down(ssum, off);
        if (kk == 0) out[(batch0 + j) * 4 + o] = ssum + fcb[o];
    }
}

extern "C" void kernel_launch(void* const* d_in, const int* in_sizes, int n_in,
                              void* d_out, int out_size, void* d_ws, size_t ws_size,
                              hipStream_t stream)
{
    (void)in_sizes; (void)n_in; (void)out_size; (void)ws_size;
    const float* x    = (const float*)d_in[0];
    const float* Wih0 = (const float*)d_in[1];
    const float* Whh0 = (const float*)d_in[2];
    const float* bih0 = (const float*)d_in[3];
    const float* bhh0 = (const float*)d_in[4];
    const float* Wih1 = (const float*)d_in[5];
    const float* Whh1 = (const float*)d_in[6];
    const float* bih1 = (const float*)d_in[7];
    const float* bhh1 = (const float*)d_in[8];
    const float* fcW  = (const float*)d_in[9];
    const float* fcb  = (const float*)d_in[10];
    float* out = (float*)d_out;

    // ws: h0ring 1MB (32 grp x 4 slot x 1024 u64) | h1ring 1MB | cflags 2KB
    u64* h0ring = (u64*)d_ws;
    u64* h1ring = (u64*)((char*)d_ws + 1048576);
    u32* cflags = (u32*)((char*)d_ws + 2097152);

    hipMemsetAsync(d_ws, 0, 2097152 + 2048, stream);   // epoch 0 == h(-1)=0

    lstm_persist<<<dim3(256), dim3(512), 0, stream>>>(
        x, Wih0, Whh0, bih0, bhh0, Wih1, Whh1, bih1, bhh1, fcW, fcb, out,
        h0ring, h1ring, cflags);
}